// Round 1
// baseline (264.125 us; speedup 1.0000x reference)
//
#include <hip/hip_runtime.h>
#include <hip/hip_bf16.h>
#include <stdint.h>

// PixproLoss: out = -(sum_masked cos_sim / count_mask), B=2048, C=256, P=49.
// R4 restructure: all global loads (m, A, b) issued in the prologue; b prefetched
// into registers in D-layout so the post-MFMA latency bubble disappears.
// inv_nm computation distributed into the B-build threads (normredW[8][64] +
// per-thread 8-way column sums) -> one fewer barrier, no single-wave inv phase.
// Phase flow: loads -> norms -> bar -> B-build -> bar -> MFMA+epilogue -> bar -> finish.

typedef __attribute__((ext_vector_type(8))) short short8;
typedef __attribute__((ext_vector_type(4))) float floatx4;

#define P 49
#define CP 12544           // C*P
#define NMASK 2401         // P*P
#define MS_STRIDE 72       // maskS LDS row stride (bf16): 64 data + 8 pad

__device__ __forceinline__ short8 cvt8(float4 a, float4 b) {
  union { __hip_bfloat162 h2; short s2[2]; } t;
  short8 r;
  t.h2 = __float22bfloat162_rn(make_float2(a.x, a.y)); r[0] = t.s2[0]; r[1] = t.s2[1];
  t.h2 = __float22bfloat162_rn(make_float2(a.z, a.w)); r[2] = t.s2[0]; r[3] = t.s2[1];
  t.h2 = __float22bfloat162_rn(make_float2(b.x, b.y)); r[4] = t.s2[0]; r[5] = t.s2[1];
  t.h2 = __float22bfloat162_rn(make_float2(b.z, b.w)); r[6] = t.s2[0]; r[7] = t.s2[1];
  return r;
}

__global__ __launch_bounds__(512, 4) void pixpro_main(
    const float* __restrict__ base, const float* __restrict__ moment,
    const int* __restrict__ A, float* __restrict__ ws_num, float* __restrict__ ws_cnt)
{
  __shared__ __align__(16) uint16_t maskS[P * MS_STRIDE];      // mask*inv_nm, bf16: 7.1 KB
  __shared__ __align__(16) float normredW[8 * 64];             // [wave][q] per-wave nm^2: 2 KB
  __shared__ __align__(16) float SQred[8 * 4 * 16 * 2];        // [w][pt][mr][{S,Q}]: 4 KB
  __shared__ float cntred[8];

  const int b    = blockIdx.x;
  const int tid  = threadIdx.x;
  const int lane = tid & 63;
  const int wv   = tid >> 6;          // 0..7
  const int mrow = lane & 15;
  const int kgrp = (lane >> 4) & 3;

  const float* gb = base   + (size_t)b * CP;
  const float* gm = moment + (size_t)b * CP;
  const int*   gA = A      + (size_t)b * NMASK;

  // ===== Prologue: issue ALL global loads upfront (m first: needed first) =====
  // m fragments (A-frag layout: lane -> m[c = mrow][q = kgrp*8 + j])
  float4 ma0[2], ma1[2], mb0[2], mb1[2];
  #pragma unroll
  for (int cti = 0; cti < 2; ++cti) {
    const int c = (2 * wv + cti) * 16 + mrow;
    const float* row = gm + c * P;
    ma0[cti] = *(const float4*)(row + kgrp * 8);
    ma1[cti] = *(const float4*)(row + kgrp * 8 + 4);
    if (kgrp < 2) {
      mb0[cti] = *(const float4*)(row + 32 + kgrp * 8);
      mb1[cti] = *(const float4*)(row + 32 + kgrp * 8 + 4);
    } else if (kgrp == 2) {
      mb0[cti] = make_float4(row[48], 0.f, 0.f, 0.f);   // q=48 only; idx <= 12543, in-bounds
      mb1[cti] = make_float4(0.f, 0.f, 0.f, 0.f);
    } else {
      mb0[cti] = make_float4(0.f, 0.f, 0.f, 0.f);
      mb1[cti] = make_float4(0.f, 0.f, 0.f, 0.f);
    }
  }

  // mask rows for B-build (registers until after barrier A)
  const bool btask = tid < P * 8;     // 392 tasks: p = tid>>3, q-group = tid&7
  const int  bp    = tid >> 3;
  const int  bqg   = tid & 7;
  const int  bq0   = bqg * 8;
  int bmask[8];
  #pragma unroll
  for (int j = 0; j < 8; ++j) bmask[j] = 0;
  if (btask) {
    const int* Ar = gA + bp * P + bq0;
    if (bqg <= 5) {                   // q = bq0..bq0+7 <= 47, fully valid
      int4 u0 = *(const int4*)(Ar);
      int4 u1 = *(const int4*)(Ar + 4);
      bmask[0] = u0.x; bmask[1] = u0.y; bmask[2] = u0.z; bmask[3] = u0.w;
      bmask[4] = u1.x; bmask[5] = u1.y; bmask[6] = u1.z; bmask[7] = u1.w;
    } else if (bqg == 6) {            // only q=48 valid (scalar avoids OOB at p=48)
      bmask[0] = Ar[0];
    }
  }

  // b prefetch in epilogue D-layout: col = lane&15 -> p, row = kgrp*4+r -> c.
  // 32 scalar dword loads/lane (4x64B segments per instr), all in flight before barrier A.
  const int pbase[4] = {0, 16, 32, 33};   // tile 3 = rows 33..48 (dedup below)
  float bv[2][4][4];
  #pragma unroll
  for (int cti = 0; cti < 2; ++cti) {
    #pragma unroll
    for (int pt = 0; pt < 4; ++pt) {
      const int pd = pbase[pt] + mrow;
      const bool pv = (pt < 3) || (mrow == 15);   // dedup rows 33..47 of tile 3
      #pragma unroll
      for (int r = 0; r < 4; ++r) {
        const int c = (2 * wv + cti) * 16 + kgrp * 4 + r;
        float v = gb[c * P + pd];
        bv[cti][pt][r] = pv ? v : 0.f;
      }
    }
  }

  // ===== norms from m (fp32, pre-cvt) + afrag build =====
  float s0[8], s1[8];
  #pragma unroll
  for (int j = 0; j < 8; ++j) { s0[j] = 0.f; s1[j] = 0.f; }
  short8 afrag[2][2];
  #pragma unroll
  for (int cti = 0; cti < 2; ++cti) {
    float4 a0 = ma0[cti], a1 = ma1[cti], b0 = mb0[cti], b1 = mb1[cti];
    s0[0] = fmaf(a0.x, a0.x, s0[0]); s0[1] = fmaf(a0.y, a0.y, s0[1]);
    s0[2] = fmaf(a0.z, a0.z, s0[2]); s0[3] = fmaf(a0.w, a0.w, s0[3]);
    s0[4] = fmaf(a1.x, a1.x, s0[4]); s0[5] = fmaf(a1.y, a1.y, s0[5]);
    s0[6] = fmaf(a1.z, a1.z, s0[6]); s0[7] = fmaf(a1.w, a1.w, s0[7]);
    s1[0] = fmaf(b0.x, b0.x, s1[0]); s1[1] = fmaf(b0.y, b0.y, s1[1]);
    s1[2] = fmaf(b0.z, b0.z, s1[2]); s1[3] = fmaf(b0.w, b0.w, s1[3]);
    s1[4] = fmaf(b1.x, b1.x, s1[4]); s1[5] = fmaf(b1.y, b1.y, s1[5]);
    s1[6] = fmaf(b1.z, b1.z, s1[6]); s1[7] = fmaf(b1.w, b1.w, s1[7]);
    afrag[cti][0] = cvt8(a0, a1);
    afrag[cti][1] = cvt8(b0, b1);
  }

  // full-wave reduce over mrow (xor 1,2,4,8): per (wv,kgrp) sum over 32 channels
  #pragma unroll
  for (int j = 0; j < 8; ++j) {
    s0[j] += __shfl_xor(s0[j], 1); s0[j] += __shfl_xor(s0[j], 2);
    s0[j] += __shfl_xor(s0[j], 4); s0[j] += __shfl_xor(s0[j], 8);
    s1[j] += __shfl_xor(s1[j], 1); s1[j] += __shfl_xor(s1[j], 2);
    s1[j] += __shfl_xor(s1[j], 4); s1[j] += __shfl_xor(s1[j], 8);
  }
  if (mrow == 0) {                    // 4 holders/wave (one per kgrp)
    float* nb_ = &normredW[wv * 64 + kgrp * 8];
    *(float4*)(nb_ + 0)  = make_float4(s0[0], s0[1], s0[2], s0[3]);
    *(float4*)(nb_ + 4)  = make_float4(s0[4], s0[5], s0[6], s0[7]);
    *(float4*)(nb_ + 32) = make_float4(s1[0], s1[1], s1[2], s1[3]);
    *(float4*)(nb_ + 36) = make_float4(s1[4], s1[5], s1[6], s1[7]);
  }
  __syncthreads();   // barrier A (also drains A + bv prefetch collectively)

  // ===== B-build: inv_nm computed in-place from normredW (no single-wave phase) =====
  // Each btask thread sums its 8 q-columns across the 8 waves: 16 ds_read_b128,
  // broadcast across same-bqg lanes, distinct bqg -> <=2-way bank alias (free).
  int cntpart = 0;
  if (btask) {
    float4 acc0 = make_float4(0.f, 0.f, 0.f, 0.f);
    float4 acc1 = make_float4(0.f, 0.f, 0.f, 0.f);
    #pragma unroll
    for (int w = 0; w < 8; ++w) {
      const float* nr = &normredW[w * 64 + bq0];
      float4 u0 = *(const float4*)(nr);
      float4 u1 = *(const float4*)(nr + 4);
      acc0.x += u0.x; acc0.y += u0.y; acc0.z += u0.z; acc0.w += u0.w;
      acc1.x += u1.x; acc1.y += u1.y; acc1.z += u1.z; acc1.w += u1.w;
    }
    float4 f0, f1;
    f0.x = bmask[0] ? (1.0f / fmaxf(sqrtf(acc0.x), 1e-6f)) : 0.f;
    f0.y = bmask[1] ? (1.0f / fmaxf(sqrtf(acc0.y), 1e-6f)) : 0.f;
    f0.z = bmask[2] ? (1.0f / fmaxf(sqrtf(acc0.z), 1e-6f)) : 0.f;
    f0.w = bmask[3] ? (1.0f / fmaxf(sqrtf(acc0.w), 1e-6f)) : 0.f;
    f1.x = bmask[4] ? (1.0f / fmaxf(sqrtf(acc1.x), 1e-6f)) : 0.f;
    f1.y = bmask[5] ? (1.0f / fmaxf(sqrtf(acc1.y), 1e-6f)) : 0.f;
    f1.z = bmask[6] ? (1.0f / fmaxf(sqrtf(acc1.z), 1e-6f)) : 0.f;
    f1.w = bmask[7] ? (1.0f / fmaxf(sqrtf(acc1.w), 1e-6f)) : 0.f;
    #pragma unroll
    for (int j = 0; j < 8; ++j) cntpart += bmask[j];
    *(short8*)&maskS[bp * MS_STRIDE + bq0] = cvt8(f0, f1);
  }
  __syncthreads();   // barrier B

  // ===== MFMA: m2 tiles; B-frag: lane -> B[k = kgrp*8+j][n = mrow] =====
  floatx4 acc[2][4];
  #pragma unroll
  for (int i = 0; i < 2; ++i)
    #pragma unroll
    for (int j = 0; j < 4; ++j) acc[i][j] = (floatx4){0.f, 0.f, 0.f, 0.f};

  #pragma unroll
  for (int kt = 0; kt < 2; ++kt) {
    short8 bfr[4];
    #pragma unroll
    for (int pt = 0; pt < 4; ++pt)
      bfr[pt] = *(const short8*)&maskS[(pbase[pt] + mrow) * MS_STRIDE + kt * 32 + kgrp * 8];
    #pragma unroll
    for (int cti = 0; cti < 2; ++cti)
      #pragma unroll
      for (int pt = 0; pt < 4; ++pt)
        acc[cti][pt] = __builtin_amdgcn_mfma_f32_16x16x32_bf16(afrag[cti][kt], bfr[pt], acc[cti][pt], 0, 0, 0);
  }

  // ===== Epilogue from prefetched registers (no memory waits) =====
  float S[4] = {0.f, 0.f, 0.f, 0.f}, Qn[4] = {0.f, 0.f, 0.f, 0.f};
  #pragma unroll
  for (int cti = 0; cti < 2; ++cti)
    #pragma unroll
    for (int pt = 0; pt < 4; ++pt)
      #pragma unroll
      for (int r = 0; r < 4; ++r) {
        S[pt]  = fmaf(bv[cti][pt][r], acc[cti][pt][r], S[pt]);
        Qn[pt] = fmaf(bv[cti][pt][r], bv[cti][pt][r], Qn[pt]);
      }

  // reduce over kgrp (lane bits 4,5)
  #pragma unroll
  for (int pt = 0; pt < 4; ++pt) {
    S[pt]  += __shfl_xor(S[pt], 16);  S[pt]  += __shfl_xor(S[pt], 32);
    Qn[pt] += __shfl_xor(Qn[pt], 16); Qn[pt] += __shfl_xor(Qn[pt], 32);
  }
  float cntf = (float)cntpart;
  #pragma unroll
  for (int off = 32; off > 0; off >>= 1) cntf += __shfl_xor(cntf, off);

  if (lane < 16) {
    #pragma unroll
    for (int pt = 0; pt < 4; ++pt)
      *(float2*)&SQred[((wv * 4 + pt) * 16 + mrow) * 2] = make_float2(S[pt], Qn[pt]);
  }
  if (lane == 0) cntred[wv] = cntf;
  __syncthreads();   // barrier C

  // ===== final: num = sum_p S[p]/max(||b_p||,eps); one wave =====
  if (tid < 64) {
    float num = 0.f, cc = 0.f;
    if (tid < P) {
      const int pt = tid >> 4;                       // 48 -> 3
      const int mr = (pt == 3) ? 15 : (tid & 15);
      float Sp = 0.f, Qp = 0.f;
      #pragma unroll
      for (int w = 0; w < 8; ++w) {
        const int idx = ((w * 4 + pt) * 16 + mr) * 2;
        Sp += SQred[idx];
        Qp += SQred[idx + 1];
      }
      num = Sp * (1.0f / fmaxf(sqrtf(Qp), 1e-6f));
    }
    if (tid < 8) cc = cntred[tid];
    #pragma unroll
    for (int off = 32; off > 0; off >>= 1) {
      num += __shfl_xor(num, off);
      cc  += __shfl_xor(cc, off);
    }
    if (tid == 0) { ws_num[b] = num; ws_cnt[b] = cc; }
  }
}

__global__ __launch_bounds__(256) void pixpro_reduce(
    const float* __restrict__ ws_num, const float* __restrict__ ws_cnt,
    float* __restrict__ out)
{
  __shared__ float rn[4], rc[4];
  float n = 0.f, c = 0.f;
  for (int i = threadIdx.x; i < 2048; i += 256) { n += ws_num[i]; c += ws_cnt[i]; }
  #pragma unroll
  for (int off = 32; off > 0; off >>= 1) {
    n += __shfl_down(n, off, 64);
    c += __shfl_down(c, off, 64);
  }
  const int wv = threadIdx.x >> 6, lane = threadIdx.x & 63;
  if (lane == 0) { rn[wv] = n; rc[wv] = c; }
  __syncthreads();
  if (threadIdx.x == 0) {
    float N = rn[0] + rn[1] + rn[2] + rn[3];
    float D = rc[0] + rc[1] + rc[2] + rc[3];
    out[0] = -(N / D);
  }
}

extern "C" void kernel_launch(void* const* d_in, const int* in_sizes, int n_in,
                              void* d_out, int out_size, void* d_ws, size_t ws_size,
                              hipStream_t stream) {
  const float* base   = (const float*)d_in[0];
  const float* moment = (const float*)d_in[1];
  const int*   A      = (const int*)d_in[2];
  float* ws_num = (float*)d_ws;          // 2048 floats
  float* ws_cnt = ws_num + 2048;         // 2048 floats
  pixpro_main<<<2048, 512, 0, stream>>>(base, moment, A, ws_num, ws_cnt);
  pixpro_reduce<<<1, 256, 0, stream>>>(ws_num, ws_cnt, (float*)d_out);
}

// Round 2
// 240.166 us; speedup vs baseline: 1.0998x; 1.0998x over previous
//
#include <hip/hip_runtime.h>
#include <hip/hip_bf16.h>
#include <stdint.h>

// PixproLoss: out = -(sum_masked cos_sim / count_mask), B=2048, C=256, P=49.
// R5 Gram reformulation: G[p,q] = sum_c b[c,p]*m[c,q] via MFMA (bf16 operands,
// fp32 accum), num = sum mask[p,q]*inv_nb[p]*inv_nm[q]*G[p,q]. Both operands
// staged transposed in LDS (bT[p][c], mT[q][c]) from coalesced float4 row loads;
// norms computed fp32 in-stream during staging. All loads consumed before the
// next barrier (R4 lesson: __syncthreads drains vmcnt(0) -> cross-barrier
// prefetch is useless and spills). 3 barriers, no post-MFMA load tail.

typedef __attribute__((ext_vector_type(8))) short short8;
typedef __attribute__((ext_vector_type(4))) float floatx4;

#define P 49
#define CP 12544           // C*P
#define NMASK 2401         // P*P
#define MT_STRIDE 264      // bf16 units; row = 528 B (16B-aligned, 33*16)
#define WS_STRIDE 72       // bf16 units; row = 144 B (16B-aligned, 9*16)

__device__ __forceinline__ uint16_t f2bf(float x) {   // RNE f32->bf16
  union { float f; uint32_t u; } v; v.f = x;
  uint32_t r = v.u + 0x7fffu + ((v.u >> 16) & 1u);
  return (uint16_t)(r >> 16);
}
__device__ __forceinline__ float bf2f(uint16_t h) {
  union { uint32_t u; float f; } v; v.u = ((uint32_t)h) << 16; return v.f;
}

// Stage one 256x49 fp32 matrix: coalesced row loads -> per-q squared-norm
// partials (fp32) -> bf16 transpose-store dstT[q][c]. nred[wv*64 + q] gets the
// per-wave (32-channel) norm^2 partial for each q (slot==q, 0..48).
__device__ __forceinline__ void stage_T(const float* __restrict__ src,
                                        uint16_t* dstT, float* nred,
                                        int wv, int mrow, int kgrp) {
  float s0[8], s1[8];
  #pragma unroll
  for (int j = 0; j < 8; ++j) { s0[j] = 0.f; s1[j] = 0.f; }

  #pragma unroll
  for (int cti = 0; cti < 2; ++cti) {
    const int c = (2 * wv + cti) * 16 + mrow;
    const float* row = src + c * P;
    float4 a0 = *(const float4*)(row + kgrp * 8);
    float4 a1 = *(const float4*)(row + kgrp * 8 + 4);
    float4 b0, b1;
    if (kgrp < 2) {
      b0 = *(const float4*)(row + 32 + kgrp * 8);
      b1 = *(const float4*)(row + 32 + kgrp * 8 + 4);
    } else if (kgrp == 2) {
      b0 = make_float4(row[48], 0.f, 0.f, 0.f);   // q=48 only; always in-bounds
      b1 = make_float4(0.f, 0.f, 0.f, 0.f);
    } else {
      b0 = make_float4(0.f, 0.f, 0.f, 0.f);
      b1 = make_float4(0.f, 0.f, 0.f, 0.f);
    }
    s0[0] = fmaf(a0.x, a0.x, s0[0]); s0[1] = fmaf(a0.y, a0.y, s0[1]);
    s0[2] = fmaf(a0.z, a0.z, s0[2]); s0[3] = fmaf(a0.w, a0.w, s0[3]);
    s0[4] = fmaf(a1.x, a1.x, s0[4]); s0[5] = fmaf(a1.y, a1.y, s0[5]);
    s0[6] = fmaf(a1.z, a1.z, s0[6]); s0[7] = fmaf(a1.w, a1.w, s0[7]);
    s1[0] = fmaf(b0.x, b0.x, s1[0]); s1[1] = fmaf(b0.y, b0.y, s1[1]);
    s1[2] = fmaf(b0.z, b0.z, s1[2]); s1[3] = fmaf(b0.w, b0.w, s1[3]);
    s1[4] = fmaf(b1.x, b1.x, s1[4]); s1[5] = fmaf(b1.y, b1.y, s1[5]);
    s1[6] = fmaf(b1.z, b1.z, s1[6]); s1[7] = fmaf(b1.w, b1.w, s1[7]);

    // transpose-store: element (c, q) -> dstT[q*MT_STRIDE + c] (bf16 scalar)
    float av[8] = {a0.x, a0.y, a0.z, a0.w, a1.x, a1.y, a1.z, a1.w};
    #pragma unroll
    for (int j = 0; j < 8; ++j)
      dstT[(kgrp * 8 + j) * MT_STRIDE + c] = f2bf(av[j]);
    if (kgrp < 2) {
      float bw[8] = {b0.x, b0.y, b0.z, b0.w, b1.x, b1.y, b1.z, b1.w};
      #pragma unroll
      for (int j = 0; j < 8; ++j)
        dstT[(32 + kgrp * 8 + j) * MT_STRIDE + c] = f2bf(bw[j]);
    } else if (kgrp == 2) {
      dstT[48 * MT_STRIDE + c] = f2bf(b0.x);
    }
  }

  // reduce squares over mrow (16 channels x 2 cti = 32 channels per (wv,kgrp))
  #pragma unroll
  for (int j = 0; j < 8; ++j) {
    s0[j] += __shfl_xor(s0[j], 1); s0[j] += __shfl_xor(s0[j], 2);
    s0[j] += __shfl_xor(s0[j], 4); s0[j] += __shfl_xor(s0[j], 8);
    s1[j] += __shfl_xor(s1[j], 1); s1[j] += __shfl_xor(s1[j], 2);
    s1[j] += __shfl_xor(s1[j], 4); s1[j] += __shfl_xor(s1[j], 8);
  }
  if (mrow == 0) {
    float* nb_ = nred + wv * 64 + kgrp * 8;
    *(float4*)(nb_ + 0)  = make_float4(s0[0], s0[1], s0[2], s0[3]);
    *(float4*)(nb_ + 4)  = make_float4(s0[4], s0[5], s0[6], s0[7]);
    *(float4*)(nb_ + 32) = make_float4(s1[0], s1[1], s1[2], s1[3]);
    *(float4*)(nb_ + 36) = make_float4(s1[4], s1[5], s1[6], s1[7]);
  }
}

__global__ __launch_bounds__(512, 4) void pixpro_main(
    const float* __restrict__ base, const float* __restrict__ moment,
    const int* __restrict__ A, float* __restrict__ ws_num, float* __restrict__ ws_cnt)
{
  __shared__ __align__(16) uint16_t mT[P * MT_STRIDE];   // m^T[q][c] bf16: 25.9 KB
  __shared__ __align__(16) uint16_t bT[P * MT_STRIDE];   // b^T[p][c] bf16: 25.9 KB
  __shared__ __align__(16) float nredM[8 * 64];          // per-wave nm^2 partials: 2 KB
  __shared__ __align__(16) float nredB[8 * 64];          // per-wave nb^2 partials: 2 KB
  __shared__ __align__(16) uint16_t wS[P * WS_STRIDE];   // mask*inv_nb*inv_nm bf16: 6.9 KB
  __shared__ float numredS[8], cntredS[8];

  const int b    = blockIdx.x;
  const int tid  = threadIdx.x;
  const int lane = tid & 63;
  const int wv   = tid >> 6;          // 0..7
  const int mrow = lane & 15;
  const int kgrp = (lane >> 4) & 3;

  const float* gb = base   + (size_t)b * CP;
  const float* gm = moment + (size_t)b * CP;
  const int*   gA = A      + (size_t)b * NMASK;

  // ---- Phase M: stage moment (loads issued+consumed here) ----
  stage_T(gm, mT, nredM, wv, mrow, kgrp);

  // ---- A-mask loads (issued now; consumed after barrier A as registers) ----
  const bool btask = tid < P * 8;     // 392 tasks: p = tid>>3, q-group = tid&7
  const int  bp    = tid >> 3;
  const int  bqg   = tid & 7;
  const int  bq0   = bqg * 8;
  int bmask[8];
  #pragma unroll
  for (int j = 0; j < 8; ++j) bmask[j] = 0;
  if (btask) {
    const int* Ar = gA + bp * P + bq0;
    if (bqg <= 5) {                   // q <= 47, fully valid
      int4 u0 = *(const int4*)(Ar);
      int4 u1 = *(const int4*)(Ar + 4);
      bmask[0] = u0.x; bmask[1] = u0.y; bmask[2] = u0.z; bmask[3] = u0.w;
      bmask[4] = u1.x; bmask[5] = u1.y; bmask[6] = u1.z; bmask[7] = u1.w;
    } else if (bqg == 6) {            // only q=48 valid
      bmask[0] = Ar[0];
    }
  }

  // ---- Phase B: stage base (loads issued+consumed here) ----
  stage_T(gb, bT, nredB, wv, mrow, kgrp);

  __syncthreads();   // barrier A: mT, bT, nredM, nredB visible

  // ---- wS build (waves 0..6 partial): wS[p][q] = mask ? inv_nb[p]*inv_nm[q] : 0 ----
  int cntpart = 0;
  if (btask) {
    float4 a0 = make_float4(0.f, 0.f, 0.f, 0.f);
    float4 a1 = make_float4(0.f, 0.f, 0.f, 0.f);
    float nb2 = 0.f;
    #pragma unroll
    for (int w = 0; w < 8; ++w) {
      const float* nr = &nredM[w * 64 + bq0];
      float4 u0 = *(const float4*)(nr);
      float4 u1 = *(const float4*)(nr + 4);
      a0.x += u0.x; a0.y += u0.y; a0.z += u0.z; a0.w += u0.w;
      a1.x += u1.x; a1.y += u1.y; a1.z += u1.z; a1.w += u1.w;
      nb2 += nredB[w * 64 + bp];
    }
    const float inb = 1.0f / fmaxf(sqrtf(nb2), 1e-6f);
    float wf[8];
    wf[0] = bmask[0] ? inb * (1.0f / fmaxf(sqrtf(a0.x), 1e-6f)) : 0.f;
    wf[1] = bmask[1] ? inb * (1.0f / fmaxf(sqrtf(a0.y), 1e-6f)) : 0.f;
    wf[2] = bmask[2] ? inb * (1.0f / fmaxf(sqrtf(a0.z), 1e-6f)) : 0.f;
    wf[3] = bmask[3] ? inb * (1.0f / fmaxf(sqrtf(a0.w), 1e-6f)) : 0.f;
    wf[4] = bmask[4] ? inb * (1.0f / fmaxf(sqrtf(a1.x), 1e-6f)) : 0.f;
    wf[5] = bmask[5] ? inb * (1.0f / fmaxf(sqrtf(a1.y), 1e-6f)) : 0.f;
    wf[6] = bmask[6] ? inb * (1.0f / fmaxf(sqrtf(a1.z), 1e-6f)) : 0.f;
    wf[7] = bmask[7] ? inb * (1.0f / fmaxf(sqrtf(a1.w), 1e-6f)) : 0.f;
    #pragma unroll
    for (int j = 0; j < 8; ++j) cntpart += bmask[j];
    short8 w8;
    #pragma unroll
    for (int j = 0; j < 8; ++j) w8[j] = (short)f2bf(wf[j]);
    *(short8*)&wS[bp * WS_STRIDE + bq0] = w8;      // 16B-aligned (144*bp + 16*bqg)
  }

  // ---- MFMA: G tiles. Wave wv: pt = wv&3, qt in {2*(wv>>2), +1}. ----
  // A-frag = bT[pbase+mrow][k], B-frag = mT[qbase+mrow][k]; both 16B reads.
  const int pt  = wv & 3;
  const int qt1i = 2 * (wv >> 2) + 1;                 // qt0 = qt1i-1 in {0,2}
  const int pbaseV  = (pt < 3) ? pt * 16 : 33;        // tiles {0,16,32,33}, dedup below
  const int qbase0  = (qt1i - 1) * 16;                // 0 or 32 (never the 33 case)
  const int qbase1  = (qt1i < 3) ? qt1i * 16 : 33;

  const int arow  = (pbaseV + mrow) * MT_STRIDE;
  const int brow0 = (qbase0 + mrow) * MT_STRIDE;
  const int brow1 = (qbase1 + mrow) * MT_STRIDE;

  floatx4 acc0 = (floatx4){0.f, 0.f, 0.f, 0.f};
  floatx4 acc1 = (floatx4){0.f, 0.f, 0.f, 0.f};
  #pragma unroll
  for (int ks = 0; ks < 8; ++ks) {
    const int off = ks * 32 + kgrp * 8;
    short8 af  = *(const short8*)&bT[arow  + off];
    short8 bf0 = *(const short8*)&mT[brow0 + off];
    short8 bf1 = *(const short8*)&mT[brow1 + off];
    acc0 = __builtin_amdgcn_mfma_f32_16x16x32_bf16(af, bf0, acc0, 0, 0, 0);
    acc1 = __builtin_amdgcn_mfma_f32_16x16x32_bf16(af, bf1, acc1, 0, 0, 0);
  }

  __syncthreads();   // barrier B: wS visible (written by waves 0..6 pre-MFMA)

  // ---- Epilogue: num_part = sum wS[p][q] * G[p][q] over owned D elems ----
  // D: q = qbase + (lane&15), p = pbase + kgrp*4 + r. Dedup tile 3 (rows 33..48).
  const bool vq1 = (qt1i < 3) || (mrow == 15);
  const int  q0r = qbase0 + mrow;
  const int  q1r = qbase1 + mrow;
  float numpart = 0.f;
  #pragma unroll
  for (int r = 0; r < 4; ++r) {
    const int rr = kgrp * 4 + r;
    const int p  = pbaseV + rr;
    const bool vp = (pt < 3) || (rr == 15);
    if (vp) {
      float w0 = bf2f(wS[p * WS_STRIDE + q0r]);
      float w1 = vq1 ? bf2f(wS[p * WS_STRIDE + q1r]) : 0.f;
      numpart = fmaf(w0, acc0[r], numpart);
      numpart = fmaf(w1, acc1[r], numpart);
    }
  }

  // full-wave reduce
  float cntf = (float)cntpart;
  #pragma unroll
  for (int off = 32; off > 0; off >>= 1) {
    numpart += __shfl_xor(numpart, off);
    cntf    += __shfl_xor(cntf, off);
  }
  if (lane == 0) { numredS[wv] = numpart; cntredS[wv] = cntf; }
  __syncthreads();   // barrier C

  if (tid < 64) {
    float n = (tid < 8) ? numredS[tid] : 0.f;
    float c = (tid < 8) ? cntredS[tid] : 0.f;
    #pragma unroll
    for (int off = 4; off > 0; off >>= 1) {
      n += __shfl_xor(n, off);
      c += __shfl_xor(c, off);
    }
    if (tid == 0) { ws_num[b] = n; ws_cnt[b] = c; }
  }
}

__global__ __launch_bounds__(256) void pixpro_reduce(
    const float* __restrict__ ws_num, const float* __restrict__ ws_cnt,
    float* __restrict__ out)
{
  __shared__ float rn[4], rc[4];
  float n = 0.f, c = 0.f;
  for (int i = threadIdx.x; i < 2048; i += 256) { n += ws_num[i]; c += ws_cnt[i]; }
  #pragma unroll
  for (int off = 32; off > 0; off >>= 1) {
    n += __shfl_down(n, off, 64);
    c += __shfl_down(c, off, 64);
  }
  const int wv = threadIdx.x >> 6, lane = threadIdx.x & 63;
  if (lane == 0) { rn[wv] = n; rc[wv] = c; }
  __syncthreads();
  if (threadIdx.x == 0) {
    float N = rn[0] + rn[1] + rn[2] + rn[3];
    float D = rc[0] + rc[1] + rc[2] + rc[3];
    out[0] = -(N / D);
  }
}

extern "C" void kernel_launch(void* const* d_in, const int* in_sizes, int n_in,
                              void* d_out, int out_size, void* d_ws, size_t ws_size,
                              hipStream_t stream) {
  const float* base   = (const float*)d_in[0];
  const float* moment = (const float*)d_in[1];
  const int*   A      = (const int*)d_in[2];
  float* ws_num = (float*)d_ws;          // 2048 floats
  float* ws_cnt = ws_num + 2048;         // 2048 floats
  pixpro_main<<<2048, 512, 0, stream>>>(base, moment, A, ws_num, ws_cnt);
  pixpro_reduce<<<1, 256, 0, stream>>>(ws_num, ws_cnt, (float*)d_out);
}